// Round 5
// baseline (375.050 us; speedup 1.0000x reference)
//
#include <hip/hip_runtime.h>
#include <math.h>
#include <stdint.h>

// Problem constants
#define NB 128
#define NR 512
#define NC 81
#define NDK 64
#define NROWS (NB * NR)  // 65536
#define LOG2E 1.44269504088896340736f

// ---------------------------------------------------------------------------
// Kernel A v3: per-row q/k projection + label (argmax) + xmax (row max).
// 256 thr / 64 rows / grid 1024. x staged in LDS [64][84] (16B-aligned rows),
// read as float4 (2-addr broadcast = free). W float4 read from GLOBAL (L1-
// resident, 41.5KB). Per c-quad: 8 LDS b128 + 4 VMEM + 128 FMA -> VALU-bound.
// ---------------------------------------------------------------------------
__global__ __launch_bounds__(256) void qk_label_kernel(
    const float* __restrict__ x,
    const float* __restrict__ Wq, const float* __restrict__ bq,
    const float* __restrict__ Wk, const float* __restrict__ bk,
    float* __restrict__ Q, float* __restrict__ K,
    int* __restrict__ label, float* __restrict__ xmax)
{
    __shared__ float xS[64][84];   // 336B rows: 16B-aligned float4 reads

    const int t = threadIdx.x;
    const int r0 = blockIdx.x * 64;

    // stage x: 5184 floats coalesced; magic div by 81 (valid < 20971)
#pragma unroll
    for (int k = 0; k < 21; ++k) {
        int flat = t + 256 * k;
        if (flat < 64 * 81) {
            int rr = (int)(((unsigned)flat * 6473u) >> 19);
            int cc = flat - 81 * rr;
            xS[rr][cc] = x[(size_t)r0 * NC + flat];
        }
    }
    __syncthreads();

    // labels / row max (first occurrence on ties, like jnp.argmax)
    if (t < 64) {
        float bv = -INFINITY; int bi = 0;
        for (int c = 0; c < 81; ++c) {
            float v = xS[t][c];
            if (v > bv) { bv = v; bi = c; }
        }
        label[r0 + t] = bi;
        xmax[r0 + t] = bv;
    }

    const int d4 = t & 31;     // col-quad id (16 Q + 16 K)
    const int rgrp = t >> 5;   // 8 rows each
    const bool isQ = d4 < 16;
    const int ocol = (isQ ? d4 : d4 - 16) * 4;
    const float* Wbase = (isQ ? Wq : Wk) + ocol;

    float acc[8][4];
#pragma unroll
    for (int i = 0; i < 8; ++i)
#pragma unroll
        for (int k = 0; k < 4; ++k) acc[i][k] = 0.f;

#pragma unroll 2
    for (int c4 = 0; c4 < 20; ++c4) {
        const float4 wv0 = *reinterpret_cast<const float4*>(&Wbase[(c4 * 4 + 0) * NDK]);
        const float4 wv1 = *reinterpret_cast<const float4*>(&Wbase[(c4 * 4 + 1) * NDK]);
        const float4 wv2 = *reinterpret_cast<const float4*>(&Wbase[(c4 * 4 + 2) * NDK]);
        const float4 wv3 = *reinterpret_cast<const float4*>(&Wbase[(c4 * 4 + 3) * NDK]);
#pragma unroll
        for (int i = 0; i < 8; ++i) {
            const float4 xv = *reinterpret_cast<const float4*>(&xS[rgrp * 8 + i][c4 * 4]);
            acc[i][0] = fmaf(xv.x, wv0.x, acc[i][0]);
            acc[i][1] = fmaf(xv.x, wv0.y, acc[i][1]);
            acc[i][2] = fmaf(xv.x, wv0.z, acc[i][2]);
            acc[i][3] = fmaf(xv.x, wv0.w, acc[i][3]);
            acc[i][0] = fmaf(xv.y, wv1.x, acc[i][0]);
            acc[i][1] = fmaf(xv.y, wv1.y, acc[i][1]);
            acc[i][2] = fmaf(xv.y, wv1.z, acc[i][2]);
            acc[i][3] = fmaf(xv.y, wv1.w, acc[i][3]);
            acc[i][0] = fmaf(xv.z, wv2.x, acc[i][0]);
            acc[i][1] = fmaf(xv.z, wv2.y, acc[i][1]);
            acc[i][2] = fmaf(xv.z, wv2.z, acc[i][2]);
            acc[i][3] = fmaf(xv.z, wv2.w, acc[i][3]);
            acc[i][0] = fmaf(xv.w, wv3.x, acc[i][0]);
            acc[i][1] = fmaf(xv.w, wv3.y, acc[i][1]);
            acc[i][2] = fmaf(xv.w, wv3.z, acc[i][2]);
            acc[i][3] = fmaf(xv.w, wv3.w, acc[i][3]);
        }
    }
    {   // remainder column c = 80
        const float4 wv = *reinterpret_cast<const float4*>(&Wbase[80 * NDK]);
#pragma unroll
        for (int i = 0; i < 8; ++i) {
            const float xv = xS[rgrp * 8 + i][80];
            acc[i][0] = fmaf(xv, wv.x, acc[i][0]);
            acc[i][1] = fmaf(xv, wv.y, acc[i][1]);
            acc[i][2] = fmaf(xv, wv.z, acc[i][2]);
            acc[i][3] = fmaf(xv, wv.w, acc[i][3]);
        }
    }

    const float* bias = isQ ? bq : bk;
    const float b0 = bias[ocol + 0], b1 = bias[ocol + 1];
    const float b2 = bias[ocol + 2], b3 = bias[ocol + 3];
    float* OUT = isQ ? Q : K;
#pragma unroll
    for (int i = 0; i < 8; ++i) {
        float4 o;
        o.x = acc[i][0] + b0; o.y = acc[i][1] + b1;
        o.z = acc[i][2] + b2; o.w = acc[i][3] + b3;
        *reinterpret_cast<float4*>(&OUT[(size_t)(r0 + rgrp * 8 + i) * NDK + ocol]) = o;
    }
}

// ---------------------------------------------------------------------------
// Kernel B v3: attention scores + softmax denom + top-10 + sparse FC.
// Grid 1024 = rg(8) * 128 + b  (same-batch blocks share an XCD's L2 for K).
// Block 256 = 4 waves; lane<->row (64 rows), wave<->j-quarter (128 j's).
// K rows read via VMEM with per-lane chunk ROTATION: lane L reads chunk
// ((L+c)&7) of each 128B half-row -> lane-dependent addrs (no SMEM
// scalarization) but all 64 lanes hit ONE cache line per instr. q is loaded
// with the same per-lane rotation so the dot is exact. Inner 16-j unroll
// gives compile-time immediate offsets (jl*256+{0,128} < 4096): the hot loop
// is pure {global_load, v_fma} + softmax/top-k, zero per-j address math.
// ---------------------------------------------------------------------------
__global__ __launch_bounds__(256, 2) void attn_kernel(
    const float* __restrict__ Q, const float* __restrict__ K,
    const int* __restrict__ label, const float* __restrict__ xmax,
    const float* __restrict__ Wfc, const float* __restrict__ bfc,
    const float* __restrict__ prior, float* __restrict__ out)
{
    __shared__ float    WfcS[NC * NC];     // 26.2 KB
    __shared__ float    bfcS[NC];
    __shared__ int      labS[NR];          // 2 KB
    __shared__ float    xmS[NR];           // 2 KB
    __shared__ uint32_t plist[4][64][10];  // 10.2 KB
    __shared__ float    lsS[4][64];        // 1 KB
    __shared__ float    fcv[64][10];       // 2.6 KB
    __shared__ int      flj[64][10];       // 2.6 KB   total ~47 KB

    const int t = threadIdx.x;
    const int b  = blockIdx.x & 127;   // batch
    const int rg = blockIdx.x >> 7;    // row-group 0..7
    const int lane = t & 63;
    const int jq = t >> 6;             // j-quarter 0..3
    const int r = rg * 64 + lane;      // row within batch
    const int g = b * NR + r;          // global row

    for (int e = t; e < NC * NC; e += 256) WfcS[e] = Wfc[e];
    if (t < NC) bfcS[t] = bfc[t];
    for (int e = t; e < NR; e += 256) { labS[e] = label[b * NR + e]; xmS[e] = xmax[b * NR + e]; }

    // rotated per-lane chunk byte-offsets within a 128-B half-row
    int koff[8];
#pragma unroll
    for (int c = 0; c < 8; ++c) koff[c] = ((lane + c) & 7) << 4;

    // q row, loaded with the same rotation (q0 = half0, q1 = half1)
    float4 q0[8], q1[8];
    {
        const char* qRow = (const char*)&Q[(size_t)g * NDK];
#pragma unroll
        for (int c = 0; c < 8; ++c) {
            q0[c] = *reinterpret_cast<const float4*>(qRow + koff[c]);
            q1[c] = *reinterpret_cast<const float4*>(qRow + 128 + koff[c]);
        }
    }

    // per-lane K base pointers (rotation folded in); stepped +4096B per 16 j
    const char* kp[8];
    {
        const char* kBase = (const char*)&K[(size_t)(b * NR + jq * 128) * NDK];
#pragma unroll
        for (int c = 0; c < 8; ++c) kp[c] = kBase + koff[c];
    }

    uint32_t tv[10];
#pragma unroll
    for (int i = 0; i < 10; ++i) tv[i] = 0u;
    float lsum = 0.f;

#pragma unroll 1
    for (int jcg = 0; jcg < 8; ++jcg) {
#pragma unroll
        for (int jl = 0; jl < 16; ++jl) {
            float4 ka[8], kb2[8];
#pragma unroll
            for (int c = 0; c < 8; ++c) {
                ka[c]  = *reinterpret_cast<const float4*>(kp[c] + jl * 256);
                kb2[c] = *reinterpret_cast<const float4*>(kp[c] + jl * 256 + 128);
            }
            float s0 = 0.f, s1 = 0.f, s2 = 0.f, s3 = 0.f;
#pragma unroll
            for (int c = 0; c < 8; ++c) {
                s0 = fmaf(q0[c].x, ka[c].x, s0);
                s1 = fmaf(q0[c].y, ka[c].y, s1);
                s2 = fmaf(q0[c].z, ka[c].z, s2);
                s3 = fmaf(q0[c].w, ka[c].w, s3);
                s0 = fmaf(q1[c].x, kb2[c].x, s0);
                s1 = fmaf(q1[c].y, kb2[c].y, s1);
                s2 = fmaf(q1[c].z, kb2[c].z, s2);
                s3 = fmaf(q1[c].w, kb2[c].w, s3);
            }
            const float sc = ((s0 + s1) + (s2 + s3)) * 0.125f;  // 1/sqrt(64)
            lsum += exp2f(sc * LOG2E);

            // pack: RNE f32->bf16, sign-flip to orderable u16, append inv idx
            uint32_t bi = __float_as_uint(sc);
            uint32_t kb16 = (bi + 0x7FFFu + ((bi >> 16) & 1u)) >> 16;
            kb16 ^= (kb16 & 0x8000u) ? 0xFFFFu : 0x8000u;
            uint32_t p = (kb16 << 9) | (uint32_t)(511 - (jq * 128 + jcg * 16 + jl));

            // branchless sorted top-10 insert
#pragma unroll
            for (int i = 0; i < 10; ++i) {
                uint32_t hi = tv[i] > p ? tv[i] : p;
                uint32_t lo = tv[i] > p ? p : tv[i];
                tv[i] = hi; p = lo;
            }
        }
#pragma unroll
        for (int c = 0; c < 8; ++c) kp[c] += 4096;
    }

    // publish partials
#pragma unroll
    for (int i = 0; i < 10; ++i) plist[jq][lane][i] = tv[i];
    lsS[jq][lane] = lsum;
    __syncthreads();

    if (t < 64) {  // jq==0 wave merges + computes contributions
#pragma unroll
        for (int f = 1; f < 4; ++f) {
#pragma unroll
            for (int i2 = 0; i2 < 10; ++i2) {
                uint32_t p = plist[f][lane][i2];
#pragma unroll
                for (int i = 0; i < 10; ++i) {
                    uint32_t hi = tv[i] > p ? tv[i] : p;
                    uint32_t lo = tv[i] > p ? p : tv[i];
                    tv[i] = hi; p = lo;
                }
            }
        }
        const float inv = 1.f /
            (lsS[0][lane] + lsS[1][lane] + lsS[2][lane] + lsS[3][lane]);
        const int li = labS[r];

        float cv[10]; int lj[10];
#pragma unroll
        for (int k2 = 0; k2 < 10; ++k2) {
            uint32_t p = tv[k2];
            int j = 511 - (int)(p & 511u);
            uint32_t kb16 = p >> 9;
            uint32_t s16 = kb16 ^ ((kb16 & 0x8000u) ? 0x8000u : 0xFFFFu);
            float scq = __uint_as_float(s16 << 16);
            float val = exp2f(scq * LOG2E) * inv;
            int l = labS[j];
            cv[k2] = (l != li) ? prior[l * NC + li] * val * xmS[j] : 0.f;
            lj[k2] = l;
        }
        // merge duplicate labels into first occurrence, then relu
#pragma unroll
        for (int a2 = 1; a2 < 10; ++a2)
#pragma unroll
            for (int b2 = 0; b2 < a2; ++b2)
                if (lj[a2] == lj[b2]) { cv[b2] += cv[a2]; cv[a2] = 0.f; break; }
#pragma unroll
        for (int k2 = 0; k2 < 10; ++k2) cv[k2] = fmaxf(cv[k2], 0.f);

#pragma unroll
        for (int k2 = 0; k2 < 10; ++k2) { fcv[lane][k2] = cv[k2]; flj[lane][k2] = lj[k2]; }
    }
    __syncthreads();

    // distributed FC epilogue: 4 threads per row, stride-4 columns
    {
        const int erow = t >> 2;   // 0..63
        const int cq = t & 3;
        const size_t eg = (size_t)(b * NR + rg * 64 + erow) * NC;
        float ecv[10]; int elj[10];
#pragma unroll
        for (int i = 0; i < 10; ++i) { ecv[i] = fcv[erow][i]; elj[i] = flj[erow][i]; }
        for (int c = cq; c < NC; c += 4) {
            float z = bfcS[c];
#pragma unroll
            for (int k2 = 0; k2 < 10; ++k2)
                z = fmaf(ecv[k2], WfcS[elj[k2] * NC + c], z);
            out[eg + c] = 1.f / (1.f + exp2f(-z * LOG2E));
        }
    }
}

// ---------------------------------------------------------------------------
extern "C" void kernel_launch(void* const* d_in, const int* in_sizes, int n_in,
                              void* d_out, int out_size, void* d_ws, size_t ws_size,
                              hipStream_t stream)
{
    const float* x     = (const float*)d_in[0];
    const float* Wq    = (const float*)d_in[1];
    const float* bq    = (const float*)d_in[2];
    const float* Wk    = (const float*)d_in[3];
    const float* bk    = (const float*)d_in[4];
    const float* Wfc   = (const float*)d_in[5];
    const float* bfc   = (const float*)d_in[6];
    const float* prior = (const float*)d_in[7];
    float* out = (float*)d_out;

    float* Q     = (float*)d_ws;
    float* K     = Q + (size_t)NROWS * NDK;
    int*   label = (int*)(K + (size_t)NROWS * NDK);
    float* xmax  = (float*)(label + NROWS);
    // NOTE: attn's last-iteration prefetch reads 256B past K's end — lands in
    // label[] (mapped workspace), values unused.

    qk_label_kernel<<<NROWS / 64, 256, 0, stream>>>(
        x, Wq, bq, Wk, bk, Q, K, label, xmax);

    attn_kernel<<<1024, 256, 0, stream>>>(
        Q, K, label, xmax, Wfc, bfc, prior, out);
}

// Round 6
// 171.911 us; speedup vs baseline: 2.1816x; 2.1816x over previous
//
#include <hip/hip_runtime.h>
#include <math.h>
#include <stdint.h>

// Problem constants
#define NB 128
#define NR 512
#define NC 81
#define NDK 64
#define NROWS (NB * NR)  // 65536
#define LOG2E 1.44269504088896340736f

typedef __attribute__((ext_vector_type(8))) short short8v;   // 8 bf16 = 4 VGPR
typedef __attribute__((ext_vector_type(4))) float float4v;   // MFMA acc

static __device__ __forceinline__ uint32_t f32_to_bf16_rne(float f) {
    uint32_t u = __float_as_uint(f);
    return (u + 0x7FFFu + ((u >> 16) & 1u)) >> 16;
}

// ---------------------------------------------------------------------------
// Kernel A: per-row q/k projection (f32 math), label/xmax from f32 x, then
// hi/lo bf16 split stored k-chunk-major: [b][kc=d>>3][512 rows][8 bf16]
// so attn's MFMA A/B fragment loads (lane: row=l&15, k=(l>>4)*8+e) are
// 256B-contiguous per 16 lanes.
// ---------------------------------------------------------------------------
__global__ __launch_bounds__(256) void qk_label_kernel(
    const float* __restrict__ x,
    const float* __restrict__ Wq, const float* __restrict__ bq,
    const float* __restrict__ Wk, const float* __restrict__ bk,
    ushort* __restrict__ Qh, ushort* __restrict__ Ql,
    ushort* __restrict__ Kh, ushort* __restrict__ Kl,
    int* __restrict__ label, float* __restrict__ xmax)
{
    __shared__ float xS[64][84];   // 336B rows: 16B-aligned float4 reads

    const int t = threadIdx.x;
    const int r0 = blockIdx.x * 64;

    // stage x: 5184 floats coalesced; magic div by 81 (valid < 20971)
#pragma unroll
    for (int k = 0; k < 21; ++k) {
        int flat = t + 256 * k;
        if (flat < 64 * 81) {
            int rr = (int)(((unsigned)flat * 6473u) >> 19);
            int cc = flat - 81 * rr;
            xS[rr][cc] = x[(size_t)r0 * NC + flat];
        }
    }
    __syncthreads();

    // labels / row max (first occurrence on ties, like jnp.argmax) — f32 exact
    if (t < 64) {
        float bv = -INFINITY; int bi = 0;
        for (int c = 0; c < 81; ++c) {
            float v = xS[t][c];
            if (v > bv) { bv = v; bi = c; }
        }
        label[r0 + t] = bi;
        xmax[r0 + t] = bv;
    }

    const int d4 = t & 31;     // col-quad id (16 Q + 16 K)
    const int rgrp = t >> 5;   // 8 rows each
    const bool isQ = d4 < 16;
    const int ocol = (isQ ? d4 : d4 - 16) * 4;
    const float* Wbase = (isQ ? Wq : Wk) + ocol;

    float acc[8][4];
#pragma unroll
    for (int i = 0; i < 8; ++i)
#pragma unroll
        for (int k = 0; k < 4; ++k) acc[i][k] = 0.f;

#pragma unroll 2
    for (int c4 = 0; c4 < 20; ++c4) {
        const float4 wv0 = *reinterpret_cast<const float4*>(&Wbase[(c4 * 4 + 0) * NDK]);
        const float4 wv1 = *reinterpret_cast<const float4*>(&Wbase[(c4 * 4 + 1) * NDK]);
        const float4 wv2 = *reinterpret_cast<const float4*>(&Wbase[(c4 * 4 + 2) * NDK]);
        const float4 wv3 = *reinterpret_cast<const float4*>(&Wbase[(c4 * 4 + 3) * NDK]);
#pragma unroll
        for (int i = 0; i < 8; ++i) {
            const float4 xv = *reinterpret_cast<const float4*>(&xS[rgrp * 8 + i][c4 * 4]);
            acc[i][0] = fmaf(xv.x, wv0.x, acc[i][0]);
            acc[i][1] = fmaf(xv.x, wv0.y, acc[i][1]);
            acc[i][2] = fmaf(xv.x, wv0.z, acc[i][2]);
            acc[i][3] = fmaf(xv.x, wv0.w, acc[i][3]);
            acc[i][0] = fmaf(xv.y, wv1.x, acc[i][0]);
            acc[i][1] = fmaf(xv.y, wv1.y, acc[i][1]);
            acc[i][2] = fmaf(xv.y, wv1.z, acc[i][2]);
            acc[i][3] = fmaf(xv.y, wv1.w, acc[i][3]);
            acc[i][0] = fmaf(xv.z, wv2.x, acc[i][0]);
            acc[i][1] = fmaf(xv.z, wv2.y, acc[i][1]);
            acc[i][2] = fmaf(xv.z, wv2.z, acc[i][2]);
            acc[i][3] = fmaf(xv.z, wv2.w, acc[i][3]);
            acc[i][0] = fmaf(xv.w, wv3.x, acc[i][0]);
            acc[i][1] = fmaf(xv.w, wv3.y, acc[i][1]);
            acc[i][2] = fmaf(xv.w, wv3.z, acc[i][2]);
            acc[i][3] = fmaf(xv.w, wv3.w, acc[i][3]);
        }
    }
    {   // remainder column c = 80
        const float4 wv = *reinterpret_cast<const float4*>(&Wbase[80 * NDK]);
#pragma unroll
        for (int i = 0; i < 8; ++i) {
            const float xv = xS[rgrp * 8 + i][80];
            acc[i][0] = fmaf(xv, wv.x, acc[i][0]);
            acc[i][1] = fmaf(xv, wv.y, acc[i][1]);
            acc[i][2] = fmaf(xv, wv.z, acc[i][2]);
            acc[i][3] = fmaf(xv, wv.w, acc[i][3]);
        }
    }

    const float* bias = isQ ? bq : bk;
    const float b0 = bias[ocol + 0], b1 = bias[ocol + 1];
    const float b2 = bias[ocol + 2], b3 = bias[ocol + 3];
    ushort* Hi = isQ ? Qh : Kh;
    ushort* Lo = isQ ? Ql : Kl;
    const int kc = ocol >> 3;
    const int sub = ocol & 7;            // 0 or 4
    const int bb = r0 >> 9;              // batch (64 | 512 so uniform)
    const int rl0 = (r0 & 511) + rgrp * 8;

#pragma unroll
    for (int i = 0; i < 8; ++i) {
        float z0 = acc[i][0] + b0, z1 = acc[i][1] + b1;
        float z2 = acc[i][2] + b2, z3 = acc[i][3] + b3;
        uint32_t h0 = f32_to_bf16_rne(z0), h1 = f32_to_bf16_rne(z1);
        uint32_t h2 = f32_to_bf16_rne(z2), h3 = f32_to_bf16_rne(z3);
        uint32_t l0 = f32_to_bf16_rne(z0 - __uint_as_float(h0 << 16));
        uint32_t l1 = f32_to_bf16_rne(z1 - __uint_as_float(h1 << 16));
        uint32_t l2 = f32_to_bf16_rne(z2 - __uint_as_float(h2 << 16));
        uint32_t l3 = f32_to_bf16_rne(z3 - __uint_as_float(h3 << 16));
        size_t base = (((size_t)bb * 8 + kc) * 512 + rl0 + i) * 8 + sub;
        uint2 hv; hv.x = h0 | (h1 << 16); hv.y = h2 | (h3 << 16);
        uint2 lv; lv.x = l0 | (l1 << 16); lv.y = l2 | (l3 << 16);
        *reinterpret_cast<uint2*>(&Hi[base]) = hv;
        *reinterpret_cast<uint2*>(&Lo[base]) = lv;
    }
}

// ---------------------------------------------------------------------------
// Kernel B: MFMA S^T = K·Q^T (swapped -> per-lane row-local softmax/top-k).
// Grid 1024: b = bid&127, ig = bid>>7 (same-batch blocks land on one XCD).
// Block 256 = 4 waves; wave owns 16 i-rows; lane: i = i0+(lane&15),
// j-quarter = lane>>4. Per 16-j tile: 6 MFMAs (hi/lo split, k=64).
// Each lane processes its 4 scores (acc regs) locally; 2-round shfl_xor
// merge (disjoint j-sets) yields per-row top-10 + denom.
// ---------------------------------------------------------------------------
__global__ __launch_bounds__(256, 4) void attn_kernel(
    const ushort* __restrict__ Qh, const ushort* __restrict__ Ql,
    const ushort* __restrict__ Kh, const ushort* __restrict__ Kl,
    const int* __restrict__ label, const float* __restrict__ xmax,
    const float* __restrict__ Wfc, const float* __restrict__ bfc,
    const float* __restrict__ prior, float* __restrict__ out)
{
    __shared__ float WfcS[NC * NC];   // 26.2 KB
    __shared__ float bfcS[NC];
    __shared__ int   labS[NR];        // 2 KB
    __shared__ float xmS[NR];         // 2 KB
    __shared__ float fcv[64][10];     // 2.6 KB
    __shared__ int   flj[64][10];     // 2.6 KB   (~36 KB total)

    const int t = threadIdx.x;
    const int b  = blockIdx.x & 127;
    const int ig = blockIdx.x >> 7;   // i-group 0..7
    const int lane = t & 63;
    const int wv = t >> 6;
    const int lr = lane & 15;         // fragment row/col within 16
    const int lq = lane >> 4;         // k-chunk / j-quarter 0..3

    for (int e = t; e < NC * NC; e += 256) WfcS[e] = Wfc[e];
    if (t < NC) bfcS[t] = bfc[t];
    for (int e = t; e < NR; e += 256) {
        labS[e] = label[b * NR + e];
        xmS[e]  = xmax[b * NR + e];
    }

    const int i = ig * 64 + wv * 16 + lr;   // row within batch for this lane

    // B-frags (Q row i): kc = ks*4+lq, 8 bf16 each
    short8v qh[2], ql[2];
#pragma unroll
    for (int ks = 0; ks < 2; ++ks) {
        size_t qoff = (((size_t)b * 8 + ks * 4 + lq) * 512 + i) * 8;
        qh[ks] = *reinterpret_cast<const short8v*>(&Qh[qoff]);
        ql[ks] = *reinterpret_cast<const short8v*>(&Ql[qoff]);
    }

    __syncthreads();   // labS/xmS fully staged before any wave's epilogue

    uint32_t tv[10];
#pragma unroll
    for (int s = 0; s < 10; ++s) tv[s] = 0u;
    float lsum = 0.f;

    // running A-frag pointers (row = jt0 + lr), advance 16 rows = 256B/tile
    const ushort* kh0 = &Kh[(((size_t)b * 8 + 0 * 4 + lq) * 512 + lr) * 8];
    const ushort* kh1 = &Kh[(((size_t)b * 8 + 1 * 4 + lq) * 512 + lr) * 8];
    const ushort* kl0 = &Kl[(((size_t)b * 8 + 0 * 4 + lq) * 512 + lr) * 8];
    const ushort* kl1 = &Kl[(((size_t)b * 8 + 1 * 4 + lq) * 512 + lr) * 8];

#pragma unroll 2
    for (int jt = 0; jt < 32; ++jt) {
        float4v c = {0.f, 0.f, 0.f, 0.f};
        {
            short8v ah0 = *reinterpret_cast<const short8v*>(kh0 + jt * 128);
            short8v al0 = *reinterpret_cast<const short8v*>(kl0 + jt * 128);
            c = __builtin_amdgcn_mfma_f32_16x16x32_bf16(ah0, qh[0], c, 0, 0, 0);
            c = __builtin_amdgcn_mfma_f32_16x16x32_bf16(al0, qh[0], c, 0, 0, 0);
            c = __builtin_amdgcn_mfma_f32_16x16x32_bf16(ah0, ql[0], c, 0, 0, 0);
        }
        {
            short8v ah1 = *reinterpret_cast<const short8v*>(kh1 + jt * 128);
            short8v al1 = *reinterpret_cast<const short8v*>(kl1 + jt * 128);
            c = __builtin_amdgcn_mfma_f32_16x16x32_bf16(ah1, qh[1], c, 0, 0, 0);
            c = __builtin_amdgcn_mfma_f32_16x16x32_bf16(al1, qh[1], c, 0, 0, 0);
            c = __builtin_amdgcn_mfma_f32_16x16x32_bf16(ah1, ql[1], c, 0, 0, 0);
        }
        // D layout (verified): col = lane&15 (=i), row = lq*4 + reg (=j)
        const int jb = jt * 16 + lq * 4;
#pragma unroll
        for (int r2 = 0; r2 < 4; ++r2) {
            const float sc = c[r2] * 0.125f;      // 1/sqrt(64)
            lsum += exp2f(sc * LOG2E);
            uint32_t kb = f32_to_bf16_rne(sc);
            kb ^= (kb & 0x8000u) ? 0xFFFFu : 0x8000u;
            uint32_t p = (kb << 9) | (uint32_t)(511 - (jb + r2));
#pragma unroll
            for (int s = 0; s < 10; ++s) {
                uint32_t hi = tv[s] > p ? tv[s] : p;
                uint32_t lo = tv[s] > p ? p : tv[s];
                tv[s] = hi; p = lo;
            }
        }
    }

    // butterfly merge over lanes sharing i (xor 16, then 32): disjoint j-sets
#pragma unroll
    for (int m = 16; m <= 32; m <<= 1) {
        lsum += __shfl_xor(lsum, m, 64);
        uint32_t inc[10];
#pragma unroll
        for (int s = 0; s < 10; ++s) inc[s] = __shfl_xor(tv[s], m, 64);
#pragma unroll
        for (int s2 = 0; s2 < 10; ++s2) {
            uint32_t p = inc[s2];
#pragma unroll
            for (int s = 0; s < 10; ++s) {
                uint32_t hi = tv[s] > p ? tv[s] : p;
                uint32_t lo = tv[s] > p ? p : tv[s];
                tv[s] = hi; p = lo;
            }
        }
    }

    // contributions: one lane per row (lq==0)
    if (lq == 0) {
        const float inv = 1.f / lsum;
        const int li = labS[i];
        float cv[10]; int lj[10];
#pragma unroll
        for (int k2 = 0; k2 < 10; ++k2) {
            uint32_t p = tv[k2];
            int j = 511 - (int)(p & 511u);
            uint32_t kb = p >> 9;
            uint32_t s16 = kb ^ ((kb & 0x8000u) ? 0x8000u : 0xFFFFu);
            float scq = __uint_as_float(s16 << 16);
            float val = exp2f(scq * LOG2E) * inv;
            int l = labS[j];
            cv[k2] = (l != li) ? prior[l * NC + li] * val * xmS[j] : 0.f;
            lj[k2] = l;
        }
        // merge duplicate labels into first occurrence, then relu
#pragma unroll
        for (int a2 = 1; a2 < 10; ++a2)
#pragma unroll
            for (int b2 = 0; b2 < a2; ++b2)
                if (lj[a2] == lj[b2]) { cv[b2] += cv[a2]; cv[a2] = 0.f; break; }
#pragma unroll
        for (int k2 = 0; k2 < 10; ++k2) cv[k2] = fmaxf(cv[k2], 0.f);

        const int rowInBlk = wv * 16 + lr;
#pragma unroll
        for (int k2 = 0; k2 < 10; ++k2) {
            fcv[rowInBlk][k2] = cv[k2];
            flj[rowInBlk][k2] = lj[k2];
        }
    }
    __syncthreads();

    // distributed FC epilogue: 4 threads per row, stride-4 columns
    {
        const int erow = t >> 2;   // 0..63
        const int cq = t & 3;
        const size_t eg = (size_t)(b * NR + ig * 64 + erow) * NC;
        float ecv[10]; int elj[10];
#pragma unroll
        for (int s = 0; s < 10; ++s) { ecv[s] = fcv[erow][s]; elj[s] = flj[erow][s]; }
        for (int c = cq; c < NC; c += 4) {
            float z = bfcS[c];
#pragma unroll
            for (int k2 = 0; k2 < 10; ++k2)
                z = fmaf(ecv[k2], WfcS[elj[k2] * NC + c], z);
            out[eg + c] = 1.f / (1.f + exp2f(-z * LOG2E));
        }
    }
}

// ---------------------------------------------------------------------------
extern "C" void kernel_launch(void* const* d_in, const int* in_sizes, int n_in,
                              void* d_out, int out_size, void* d_ws, size_t ws_size,
                              hipStream_t stream)
{
    const float* x     = (const float*)d_in[0];
    const float* Wq    = (const float*)d_in[1];
    const float* bq    = (const float*)d_in[2];
    const float* Wk    = (const float*)d_in[3];
    const float* bk    = (const float*)d_in[4];
    const float* Wfc   = (const float*)d_in[5];
    const float* bfc   = (const float*)d_in[6];
    const float* prior = (const float*)d_in[7];
    float* out = (float*)d_out;

    // workspace: 4 x (65536*64) bf16 arrays + label + xmax  (~34.1 MB)
    ushort* Qh = (ushort*)d_ws;
    ushort* Ql = Qh + (size_t)NROWS * NDK;
    ushort* Kh = Ql + (size_t)NROWS * NDK;
    ushort* Kl = Kh + (size_t)NROWS * NDK;
    int*   label = (int*)(Kl + (size_t)NROWS * NDK);
    float* xmax  = (float*)(label + NROWS);

    qk_label_kernel<<<NROWS / 64, 256, 0, stream>>>(
        x, Wq, bq, Wk, bk, Qh, Ql, Kh, Kl, label, xmax);

    attn_kernel<<<1024, 256, 0, stream>>>(
        Qh, Ql, Kh, Kl, label, xmax, Wfc, bfc, prior, out);
}

// Round 7
// 161.016 us; speedup vs baseline: 2.3293x; 1.0677x over previous
//
#include <hip/hip_runtime.h>
#include <math.h>
#include <stdint.h>

// Problem constants
#define NB 128
#define NR 512
#define NC 81
#define NDK 64
#define NROWS (NB * NR)  // 65536

typedef __attribute__((ext_vector_type(8))) short short8v;   // 8 bf16 = 4 VGPR
typedef __attribute__((ext_vector_type(4))) float float4v;   // MFMA acc

static __device__ __forceinline__ uint32_t f32_to_bf16_rne(float f) {
    uint32_t u = __float_as_uint(f);
    return (u + 0x7FFFu + ((u >> 16) & 1u)) >> 16;
}

// ---------------------------------------------------------------------------
// Kernel A: per-row q/k projection (f32 math), label/xmax from f32 x.
// Output: hi/lo bf16 split in k-chunk-major layout [b][kc=d>>3][512][8],
// written via LDS repack so global stores are fully coalesced (R6's direct
// scattered 8B stores were the regression).
// ---------------------------------------------------------------------------
__global__ __launch_bounds__(256) void qk_label_kernel(
    const float* __restrict__ x,
    const float* __restrict__ Wq, const float* __restrict__ bq,
    const float* __restrict__ Wk, const float* __restrict__ bk,
    ushort* __restrict__ Qh, ushort* __restrict__ Ql,
    ushort* __restrict__ Kh, ushort* __restrict__ Kl,
    int* __restrict__ label, float* __restrict__ xmax)
{
    __shared__ union {
        float  xS[64][84];      // 21504 B (336B rows, 16B-aligned float4)
        ushort pk[4][8][520];   // 33280 B: 4 arrays x 8 kc-planes x (64*8 + pad)
    } uA;

    const int t = threadIdx.x;
    const int r0 = blockIdx.x * 64;

    // stage x: 5184 floats coalesced; magic div by 81 (valid < 20971)
#pragma unroll
    for (int k = 0; k < 21; ++k) {
        int flat = t + 256 * k;
        if (flat < 64 * 81) {
            int rr = (int)(((unsigned)flat * 6473u) >> 19);
            int cc = flat - 81 * rr;
            uA.xS[rr][cc] = x[(size_t)r0 * NC + flat];
        }
    }
    __syncthreads();

    // labels / row max (first occurrence on ties, like jnp.argmax) — f32 exact
    if (t < 64) {
        float bv = -INFINITY; int bi = 0;
        for (int c = 0; c < 81; ++c) {
            float v = uA.xS[t][c];
            if (v > bv) { bv = v; bi = c; }
        }
        label[r0 + t] = bi;
        xmax[r0 + t] = bv;
    }

    const int d4 = t & 31;     // col-quad id (16 Q + 16 K)
    const int rgrp = t >> 5;   // 8 rows each
    const bool isQ = d4 < 16;
    const int ocol = (isQ ? d4 : d4 - 16) * 4;
    const float* Wbase = (isQ ? Wq : Wk) + ocol;

    float acc[8][4];
#pragma unroll
    for (int i = 0; i < 8; ++i)
#pragma unroll
        for (int k = 0; k < 4; ++k) acc[i][k] = 0.f;

#pragma unroll 2
    for (int c4 = 0; c4 < 20; ++c4) {
        const float4 wv0 = *reinterpret_cast<const float4*>(&Wbase[(c4 * 4 + 0) * NDK]);
        const float4 wv1 = *reinterpret_cast<const float4*>(&Wbase[(c4 * 4 + 1) * NDK]);
        const float4 wv2 = *reinterpret_cast<const float4*>(&Wbase[(c4 * 4 + 2) * NDK]);
        const float4 wv3 = *reinterpret_cast<const float4*>(&Wbase[(c4 * 4 + 3) * NDK]);
#pragma unroll
        for (int i = 0; i < 8; ++i) {
            const float4 xv = *reinterpret_cast<const float4*>(&uA.xS[rgrp * 8 + i][c4 * 4]);
            acc[i][0] = fmaf(xv.x, wv0.x, acc[i][0]);
            acc[i][1] = fmaf(xv.x, wv0.y, acc[i][1]);
            acc[i][2] = fmaf(xv.x, wv0.z, acc[i][2]);
            acc[i][3] = fmaf(xv.x, wv0.w, acc[i][3]);
            acc[i][0] = fmaf(xv.y, wv1.x, acc[i][0]);
            acc[i][1] = fmaf(xv.y, wv1.y, acc[i][1]);
            acc[i][2] = fmaf(xv.y, wv1.z, acc[i][2]);
            acc[i][3] = fmaf(xv.y, wv1.w, acc[i][3]);
            acc[i][0] = fmaf(xv.z, wv2.x, acc[i][0]);
            acc[i][1] = fmaf(xv.z, wv2.y, acc[i][1]);
            acc[i][2] = fmaf(xv.z, wv2.z, acc[i][2]);
            acc[i][3] = fmaf(xv.z, wv2.w, acc[i][3]);
            acc[i][0] = fmaf(xv.w, wv3.x, acc[i][0]);
            acc[i][1] = fmaf(xv.w, wv3.y, acc[i][1]);
            acc[i][2] = fmaf(xv.w, wv3.z, acc[i][2]);
            acc[i][3] = fmaf(xv.w, wv3.w, acc[i][3]);
        }
    }
    {   // remainder column c = 80
        const float4 wv = *reinterpret_cast<const float4*>(&Wbase[80 * NDK]);
#pragma unroll
        for (int i = 0; i < 8; ++i) {
            const float xv = uA.xS[rgrp * 8 + i][80];
            acc[i][0] = fmaf(xv, wv.x, acc[i][0]);
            acc[i][1] = fmaf(xv, wv.y, acc[i][1]);
            acc[i][2] = fmaf(xv, wv.z, acc[i][2]);
            acc[i][3] = fmaf(xv, wv.w, acc[i][3]);
        }
    }

    const float* bias = isQ ? bq : bk;
    const float b0 = bias[ocol + 0], b1 = bias[ocol + 1];
    const float b2 = bias[ocol + 2], b3 = bias[ocol + 3];
    const int aH = isQ ? 0 : 2;          // Qh/Ql = 0/1, Kh/Kl = 2/3
    const int kc = ocol >> 3;
    const int sub = ocol & 7;            // 0 or 4

    __syncthreads();   // all xS reads (compute + label wave) complete

#pragma unroll
    for (int i = 0; i < 8; ++i) {
        float z0 = acc[i][0] + b0, z1 = acc[i][1] + b1;
        float z2 = acc[i][2] + b2, z3 = acc[i][3] + b3;
        uint32_t h0 = f32_to_bf16_rne(z0), h1 = f32_to_bf16_rne(z1);
        uint32_t h2 = f32_to_bf16_rne(z2), h3 = f32_to_bf16_rne(z3);
        uint32_t l0 = f32_to_bf16_rne(z0 - __uint_as_float(h0 << 16));
        uint32_t l1 = f32_to_bf16_rne(z1 - __uint_as_float(h1 << 16));
        uint32_t l2 = f32_to_bf16_rne(z2 - __uint_as_float(h2 << 16));
        uint32_t l3 = f32_to_bf16_rne(z3 - __uint_as_float(h3 << 16));
        uint2 hv; hv.x = h0 | (h1 << 16); hv.y = h2 | (h3 << 16);
        uint2 lv; lv.x = l0 | (l1 << 16); lv.y = l2 | (l3 << 16);
        const int lofs = (rgrp * 8 + i) * 8 + sub;   // row-in-block * 8 + sub
        *reinterpret_cast<uint2*>(&uA.pk[aH][kc][lofs])     = hv;
        *reinterpret_cast<uint2*>(&uA.pk[aH + 1][kc][lofs]) = lv;
    }
    __syncthreads();

    // coalesced copy-out: 4096 uint2 total, 16 per thread
    const int bb = r0 >> 9;       // batch
    const int rl0 = r0 & 511;     // row base within batch
#pragma unroll
    for (int m = 0; m < 16; ++m) {
        int F = t + 256 * m;              // 0..4095
        int a = F >> 10, rem = F & 1023;  // a uniform per m
        int kc2 = rem >> 7, f4 = rem & 127;
        uint2 v = *reinterpret_cast<const uint2*>(&uA.pk[a][kc2][f4 * 4]);
        ushort* dst = (a == 0) ? Qh : (a == 1) ? Ql : (a == 2) ? Kh : Kl;
        *(reinterpret_cast<uint2*>(dst + (((size_t)bb * 8 + kc2) * 512 + rl0) * 8) + f4) = v;
    }
}

// ---------------------------------------------------------------------------
// Kernel B: MFMA S^T = K·Q^T (swapped -> per-lane row-local softmax/top-k).
// Changes vs R6: chain-free 19-op sorted insert (all ops read OLD regs ->
// full ILP), orderable-key pack on UNSCALED scores (0.125 applied at decode;
// exact for bf16), __expf/__fdividef fast paths, split MFMA accumulators.
// ---------------------------------------------------------------------------
__global__ __launch_bounds__(256, 4) void attn_kernel(
    const ushort* __restrict__ Qh, const ushort* __restrict__ Ql,
    const ushort* __restrict__ Kh, const ushort* __restrict__ Kl,
    const int* __restrict__ label, const float* __restrict__ xmax,
    const float* __restrict__ Wfc, const float* __restrict__ bfc,
    const float* __restrict__ prior, float* __restrict__ out)
{
    __shared__ float WfcS[NC * NC];   // 26.2 KB
    __shared__ float bfcS[NC];
    __shared__ int   labS[NR];        // 2 KB
    __shared__ float xmS[NR];         // 2 KB
    __shared__ float fcv[64][10];     // 2.6 KB
    __shared__ int   flj[64][10];     // 2.6 KB

    const int t = threadIdx.x;
    const int b  = blockIdx.x & 127;
    const int ig = blockIdx.x >> 7;   // i-group 0..7
    const int lane = t & 63;
    const int wv = t >> 6;
    const int lr = lane & 15;         // fragment row/col within 16
    const int lq = lane >> 4;         // k-chunk / j-quarter 0..3

    for (int e = t; e < NC * NC; e += 256) WfcS[e] = Wfc[e];
    if (t < NC) bfcS[t] = bfc[t];
    for (int e = t; e < NR; e += 256) {
        labS[e] = label[b * NR + e];
        xmS[e]  = xmax[b * NR + e];
    }

    const int i = ig * 64 + wv * 16 + lr;   // row within batch for this lane

    // B-frags (Q row i): kc = ks*4+lq, 8 bf16 each
    short8v qh[2], ql[2];
#pragma unroll
    for (int ks = 0; ks < 2; ++ks) {
        size_t qoff = (((size_t)b * 8 + ks * 4 + lq) * 512 + i) * 8;
        qh[ks] = *reinterpret_cast<const short8v*>(&Qh[qoff]);
        ql[ks] = *reinterpret_cast<const short8v*>(&Ql[qoff]);
    }

    __syncthreads();   // labS/xmS fully staged before any later reads

    uint32_t tv[10];
#pragma unroll
    for (int s = 0; s < 10; ++s) tv[s] = 0u;
    float lsum = 0.f;
    const int invb = 511 - lq * 4;

    // running A-frag pointers (row = jt*16 + lr), advance 256B per tile
    const ushort* kh0 = &Kh[(((size_t)b * 8 + 0 * 4 + lq) * 512 + lr) * 8];
    const ushort* kh1 = &Kh[(((size_t)b * 8 + 1 * 4 + lq) * 512 + lr) * 8];
    const ushort* kl0 = &Kl[(((size_t)b * 8 + 0 * 4 + lq) * 512 + lr) * 8];
    const ushort* kl1 = &Kl[(((size_t)b * 8 + 1 * 4 + lq) * 512 + lr) * 8];

#pragma unroll 2
    for (int jt = 0; jt < 32; ++jt) {
        float4v ca = {0.f, 0.f, 0.f, 0.f};
        float4v cb = {0.f, 0.f, 0.f, 0.f};
        {
            short8v ah0 = *reinterpret_cast<const short8v*>(kh0 + jt * 128);
            short8v al0 = *reinterpret_cast<const short8v*>(kl0 + jt * 128);
            ca = __builtin_amdgcn_mfma_f32_16x16x32_bf16(ah0, qh[0], ca, 0, 0, 0);
            ca = __builtin_amdgcn_mfma_f32_16x16x32_bf16(al0, qh[0], ca, 0, 0, 0);
            ca = __builtin_amdgcn_mfma_f32_16x16x32_bf16(ah0, ql[0], ca, 0, 0, 0);
        }
        {
            short8v ah1 = *reinterpret_cast<const short8v*>(kh1 + jt * 128);
            short8v al1 = *reinterpret_cast<const short8v*>(kl1 + jt * 128);
            cb = __builtin_amdgcn_mfma_f32_16x16x32_bf16(ah1, qh[1], cb, 0, 0, 0);
            cb = __builtin_amdgcn_mfma_f32_16x16x32_bf16(al1, qh[1], cb, 0, 0, 0);
            cb = __builtin_amdgcn_mfma_f32_16x16x32_bf16(ah1, ql[1], cb, 0, 0, 0);
        }
        const int invt = invb - jt * 16;
#pragma unroll
        for (int r2 = 0; r2 < 4; ++r2) {
            const float cf = ca[r2] + cb[r2];     // UNSCALED score*8
            lsum += __expf(cf * 0.125f);
            // orderable key: flip to monotone u32, RNE-truncate to 16 bits
            uint32_t u = __float_as_uint(cf);
            uint32_t sgn = (uint32_t)((int32_t)u >> 31);
            uint32_t k32 = u ^ (sgn | 0x80000000u);
            uint32_t kb = (k32 + 0x7FFFu + ((k32 >> 16) & 1u)) >> 16;
            uint32_t p = (kb << 9) | (uint32_t)(invt - r2);
            // chain-free sorted top-10 insert (reads OLD regs only)
#pragma unroll
            for (int s = 9; s >= 1; --s) {
                uint32_t mn = tv[s - 1] < p ? tv[s - 1] : p;
                tv[s] = tv[s] > mn ? tv[s] : mn;
            }
            tv[0] = tv[0] > p ? tv[0] : p;
        }
    }

    // butterfly merge over lanes sharing i (xor 16, then 32): disjoint j-sets
#pragma unroll
    for (int m = 16; m <= 32; m <<= 1) {
        lsum += __shfl_xor(lsum, m, 64);
        uint32_t inc[10];
#pragma unroll
        for (int s = 0; s < 10; ++s) inc[s] = __shfl_xor(tv[s], m, 64);
#pragma unroll
        for (int s2 = 0; s2 < 10; ++s2) {
            uint32_t p = inc[s2];
#pragma unroll
            for (int s = 9; s >= 1; --s) {
                uint32_t mn = tv[s - 1] < p ? tv[s - 1] : p;
                tv[s] = tv[s] > mn ? tv[s] : mn;
            }
            tv[0] = tv[0] > p ? tv[0] : p;
        }
    }

    // contributions: one lane per row (lq==0)
    if (lq == 0) {
        const float inv = __fdividef(1.f, lsum);
        const int li = labS[i];
        float cv[10]; int lj[10];
#pragma unroll
        for (int k2 = 0; k2 < 10; ++k2) {
            uint32_t p = tv[k2];
            int j = 511 - (int)(p & 511u);
            uint32_t kb = p >> 9;
            uint32_t s16 = (kb & 0x8000u) ? (kb ^ 0x8000u) : (kb ^ 0xFFFFu);
            float scq = __uint_as_float(s16 << 16);     // unscaled quantized
            float val = __expf(scq * 0.125f) * inv;
            int l = labS[j];
            cv[k2] = (l != li) ? prior[l * NC + li] * val * xmS[j] : 0.f;
            lj[k2] = l;
        }
        // merge duplicate labels into first occurrence, then relu
#pragma unroll
        for (int a2 = 1; a2 < 10; ++a2)
#pragma unroll
            for (int b2 = 0; b2 < a2; ++b2)
                if (lj[a2] == lj[b2]) { cv[b2] += cv[a2]; cv[a2] = 0.f; break; }
#pragma unroll
        for (int k2 = 0; k2 < 10; ++k2) cv[k2] = fmaxf(cv[k2], 0.f);

        const int rowInBlk = wv * 16 + lr;
#pragma unroll
        for (int k2 = 0; k2 < 10; ++k2) {
            fcv[rowInBlk][k2] = cv[k2];
            flj[rowInBlk][k2] = lj[k2];
        }
    }
    __syncthreads();

    // distributed FC epilogue: 4 threads per row, stride-4 columns
    {
        const int erow = t >> 2;   // 0..63
        const int cq = t & 3;
        const size_t eg = (size_t)(b * NR + ig * 64 + erow) * NC;
        float ecv[10]; int elj[10];
#pragma unroll
        for (int s = 0; s < 10; ++s) { ecv[s] = fcv[erow][s]; elj[s] = flj[erow][s]; }
        for (int c = cq; c < NC; c += 4) {
            float z = bfcS[c];
#pragma unroll
            for (int k2 = 0; k2 < 10; ++k2)
                z = fmaf(ecv[k2], WfcS[elj[k2] * NC + c], z);
            out[eg + c] = __fdividef(1.f, 1.f + __expf(-z));
        }
    }
}

// ---------------------------------------------------------------------------
extern "C" void kernel_launch(void* const* d_in, const int* in_sizes, int n_in,
                              void* d_out, int out_size, void* d_ws, size_t ws_size,
                              hipStream_t stream)
{
    const float* x     = (const float*)d_in[0];
    const float* Wq    = (const float*)d_in[1];
    const float* bq    = (const float*)d_in[2];
    const float* Wk    = (const float*)d_in[3];
    const float* bk    = (const float*)d_in[4];
    const float* Wfc   = (const float*)d_in[5];
    const float* bfc   = (const float*)d_in[6];
    const float* prior = (const float*)d_in[7];
    float* out = (float*)d_out;

    // workspace: 4 x (65536*64) bf16 arrays + label + xmax  (~34.1 MB)
    ushort* Qh = (ushort*)d_ws;
    ushort* Ql = Qh + (size_t)NROWS * NDK;
    ushort* Kh = Ql + (size_t)NROWS * NDK;
    ushort* Kl = Kh + (size_t)NROWS * NDK;
    int*   label = (int*)(Kl + (size_t)NROWS * NDK);
    float* xmax  = (float*)(label + NROWS);

    qk_label_kernel<<<NROWS / 64, 256, 0, stream>>>(
        x, Wq, bq, Wk, bk, Qh, Ql, Kh, Kl, label, xmax);

    attn_kernel<<<1024, 256, 0, stream>>>(
        Qh, Ql, Kh, Kl, label, xmax, Wfc, bfc, prior, out);
}